// Round 3
// baseline (514.603 us; speedup 1.0000x reference)
//
#include <hip/hip_runtime.h>
#include <hip/hip_bf16.h>
#include <stdint.h>

#define N_TOK 4096
#define DDIM  1024
#define HDIM  768
#define NEXP  23
#define TOPK  3
#define MAXTILE 152            // <=119 routed tiles + 32 shared tiles
#define SLOTS   19456

typedef float floatx4 __attribute__((ext_vector_type(4)));
typedef short short8  __attribute__((ext_vector_type(8)));

__device__ __forceinline__ short f2bf(float f) {
    __hip_bfloat16 h = __float2bfloat16(f);
    return *reinterpret_cast<short*>(&h);
}
__device__ __forceinline__ float bf2f(short s) {
    unsigned u = ((unsigned)(unsigned short)s) << 16;
    return __uint_as_float(u);
}
__device__ __forceinline__ float gelu_erf(float v) {
    return 0.5f * v * (1.0f + erff(v * 0.70710678118654752f));
}
// async global->LDS, 16B/lane; LDS dest wave-uniform base (HW adds lane*16)
__device__ __forceinline__ void gl_lds16(const short* g, short* l) {
    __builtin_amdgcn_global_load_lds(
        (const __attribute__((address_space(1))) void*)g,
        (__attribute__((address_space(3))) void*)l, 16, 0, 0);
}

// block-role bases for the fused prep kernel (no weight processing anymore)
#define PREP_GATE   1024
#define PREP_XCVT   N_TOK                 // 4096 blocks
#define PREP_BIAS   168                   // 24*(H+D)/256
#define PREP_GRID   (PREP_GATE + PREP_XCVT + PREP_BIAS)

// ------------------- fused: gate+topk | x fp32->bf16 | bias concat
__global__ __launch_bounds__(256) void prep_kernel(
    const float* __restrict__ x, const float* __restrict__ gate_W,
    const float* __restrict__ gate_b, const float* __restrict__ route_bias,
    int* __restrict__ top_idx, float* __restrict__ top_w,
    float* __restrict__ psum_part, short* __restrict__ xb,
    const float* __restrict__ b1, const float* __restrict__ sb1,
    const float* __restrict__ b2, const float* __restrict__ sb2,
    float* __restrict__ bias1_all, float* __restrict__ bias2_all)
{
    __shared__ float ldsbuf[1728];        // gate: gw[64][25] + ps[4][23]
    const int b = blockIdx.x;
    if (b >= PREP_GATE) {
        const int bb = b - PREP_GATE;
        if (bb < PREP_XCVT) {             // x convert: one float4/thread
            size_t i = (size_t)bb * 256 + threadIdx.x;
            float4 v = ((const float4*)x)[i];
            short4 o;
            o.x = f2bf(v.x); o.y = f2bf(v.y); o.z = f2bf(v.z); o.w = f2bf(v.w);
            ((short4*)xb)[i] = o;
        } else {                          // bias concat
            int i = (bb - PREP_XCVT) * 256 + threadIdx.x;
            if (i < 24 * HDIM) {
                bias1_all[i] = (i < NEXP * HDIM) ? b1[i] : sb1[i - NEXP * HDIM];
            } else {
                int j = i - 24 * HDIM;
                if (j < 24 * DDIM)
                    bias2_all[j] = (j < NEXP * DDIM) ? b2[j] : sb2[j - NEXP * DDIM];
            }
        }
        return;
    }
    // ---- gate: one wave per token, fp32-exact
    const int wave = threadIdx.x >> 6, lane = threadIdx.x & 63;
    const int n = b * 4 + wave;

    float (*gw)[25]   = (float(*)[25])ldsbuf;
    float (*ps)[NEXP] = (float(*)[NEXP])(ldsbuf + 1600);

    float acc[NEXP];
#pragma unroll
    for (int e = 0; e < NEXP; e++) acc[e] = 0.f;

    const float* xr = x + (size_t)n * DDIM;
    for (int c0 = 0; c0 < DDIM; c0 += 64) {
        for (int idx = threadIdx.x; idx < 64 * NEXP; idx += 256)
            gw[idx / NEXP][idx % NEXP] = gate_W[(size_t)c0 * NEXP + idx];
        __syncthreads();
        float xd = xr[c0 + lane];
#pragma unroll
        for (int e = 0; e < NEXP; e++) acc[e] += xd * gw[lane][e];
        __syncthreads();
    }
    for (int off = 32; off > 0; off >>= 1) {
#pragma unroll
        for (int e = 0; e < NEXP; e++) acc[e] += __shfl_xor(acc[e], off, 64);
    }

    float p[NEXP], s = 0.f;
#pragma unroll
    for (int e = 0; e < NEXP; e++) {
        p[e] = 1.f / (1.f + expf(-(acc[e] + gate_b[e])));
        s += p[e];
    }
    const float inv = 1.f / s;

    if (lane == 0) {
#pragma unroll
        for (int e = 0; e < NEXP; e++) ps[wave][e] = p[e] * inv;
        // top-3, strict > picks lowest index on ties (lax.top_k rule)
        int idx[TOPK]; float w[TOPK]; bool used[NEXP] = {};
        for (int k = 0; k < TOPK; k++) {
            float best = -1e30f; int bi = 0;
            for (int e = 0; e < NEXP; e++) {
                if (!used[e]) {
                    float sc = p[e] + route_bias[e];
                    if (sc > best) { best = sc; bi = e; }
                }
            }
            used[bi] = true; idx[k] = bi; w[k] = p[bi];
        }
        float wsum = w[0] + w[1] + w[2];
        for (int k = 0; k < TOPK; k++) {
            top_idx[n * TOPK + k] = idx[k];
            top_w[n * TOPK + k]   = w[k] / wsum;
        }
    }
    __syncthreads();
    if (threadIdx.x < NEXP) {
        int e = threadIdx.x;
        psum_part[(size_t)b * NEXP + e] =
            ps[0][e] + ps[1][e] + ps[2][e] + ps[3][e];
    }
}

// ---------- plan+scatter: counts, aux loss, tile table, slot maps (1 block)
__global__ __launch_bounds__(256) void plan_kernel(
    const int* __restrict__ top_idx, const float* __restrict__ psum_part,
    int* __restrict__ tile_e, int* __restrict__ tok_of_slot,
    int* __restrict__ slot_of_tok, float* __restrict__ out_aux)
{
    __shared__ int   cnt[NEXP];
    __shared__ float psum[NEXP];
    __shared__ int   tbase[NEXP + 1];
    __shared__ int   lcur[NEXP];
    const int t = threadIdx.x;
    if (t < NEXP) { cnt[t] = 0; psum[t] = 0.f; lcur[t] = 0; }
    __syncthreads();

    for (int i = t; i < N_TOK * TOPK; i += 256)
        atomicAdd(&cnt[top_idx[i]], 1);

    float loc[NEXP];
#pragma unroll
    for (int e = 0; e < NEXP; e++) loc[e] = 0.f;
    for (int b = t; b < N_TOK / 4; b += 256) {
        const float* row = psum_part + (size_t)b * NEXP;
#pragma unroll
        for (int e = 0; e < NEXP; e++) loc[e] += row[e];
    }
#pragma unroll
    for (int e = 0; e < NEXP; e++) atomicAdd(&psum[e], loc[e]);
    __syncthreads();

    if (t == 0) {
        int tb = 0; float aux = 0.f;
        for (int e = 0; e < NEXP; e++) {
            tbase[e] = tb;
            float P = psum[e] / (float)N_TOK;
            float F = (float)NEXP * (float)cnt[e] / ((float)TOPK * (float)N_TOK);
            aux += P * F;
            tb += (cnt[e] + 127) >> 7;
        }
        tbase[NEXP] = tb;
        *out_aux = aux;
    }
    __syncthreads();
    const int tr = tbase[NEXP];
    const int P  = tr << 7;
    for (int i = t; i < MAXTILE; i += 256) {
        int v = -1;
        if (i < tr) {
            for (int e = 0; e < NEXP; e++)
                if (i >= tbase[e] && i < tbase[e + 1]) v = e;
        } else if (i < tr + N_TOK / 128) v = NEXP;
        tile_e[i] = v;
    }
    // scatter (LDS-atomic cursors; pad slots left undefined, gemm clamps)
    for (int i = t; i < N_TOK * TOPK; i += 256) {
        const int e = top_idx[i];
        const int pos = atomicAdd(&lcur[e], 1);
        const int slot = (tbase[e] << 7) + pos;
        const int n = i / 3, k = i - n * 3;
        tok_of_slot[slot] = n;
        slot_of_tok[n * 4 + k] = slot;
    }
    for (int n = t; n < N_TOK; n += 256) {
        tok_of_slot[P + n] = n;            // shared expert: identity mapping
        slot_of_tok[n * 4 + 3] = P + n;
    }
}

// --------------------------------------------------------------- unified GEMM
// 128x128 tile, BK=32, 3-stage pipeline. A: global_load_lds (bf16, swizzled
// source). B: NATIVE fp32 weights, register-staged (16 coalesced loads ->
// f2bf -> 2x ds_write_b128 into fragment layout), 2 reg-sets deep. Counted
// vmcnt(18) keeps 1 full stage (2 A-dma + 16 B-loads) in flight across
// barriers. 16B XOR swizzle on the fragment layout cuts ds_read_b128
// conflicts 8-way -> 2-way. No W1T/W2T round-trip through HBM anymore.
template <bool FFN1>
__global__ __launch_bounds__(256) void gemm_kernel(
    const short* __restrict__ Abase, const int* __restrict__ tok_of_slot,
    const int* __restrict__ tile_e, const float* __restrict__ Wfp,
    const float* __restrict__ Wsh, const float* __restrict__ bias_all,
    short* __restrict__ outb)
{
    constexpr int KD = FFN1 ? DDIM : HDIM;
    constexpr int NC = FFN1 ? HDIM : DDIM;
    constexpr int KI = KD / 32;
    constexpr int GX = NC / 128;
    constexpr int NWG = GX * MAXTILE;
    constexpr int Q = NWG / 8, RM = NWG % 8;

    int bid = blockIdx.y * GX + blockIdx.x;
    {   // bijective chunked XCD swizzle: same-expert tiles cluster on one XCD
        const int xcd = bid & 7, off = bid >> 3;
        bid = (xcd < RM) ? (xcd * (Q + 1) + off)
                         : (RM * (Q + 1) + (xcd - RM) * Q + off);
    }
    const int tile = bid / GX;
    const int e = tile_e[tile];
    if (e < 0) return;
    const int slot0 = tile * 128;
    const int n0 = (bid - tile * GX) * 128;

    __shared__ short smem[3 * 4096 * 2];       // 48 KiB: As[3] | Bs[3]
    short* const As = smem;
    short* const Bs = smem + 3 * 4096;

    const int t = threadIdx.x;
    const int w = t >> 6, l = t & 63;
    const int quad = l >> 4, l16 = l & 15;
    const int wr = w >> 1, wc = w & 1;

    // ---- A staging (gl_lds16): swizzled k-octet so LDS holds the XOR layout
    const int ra0 = w * 32 + (l >> 2);
    const int ra1 = ra0 + 16;
    const int ko  = (((l & 3) ^ ((l >> 4) & 3)) << 3);   // shorts

    const short *ap0, *ap1;
    if constexpr (FFN1) {
        int t0 = tok_of_slot[slot0 + ra0];
        int t1 = tok_of_slot[slot0 + ra1];
        t0 = ((unsigned)t0 < (unsigned)N_TOK) ? t0 : 0;  // pad slots: any valid row
        t1 = ((unsigned)t1 < (unsigned)N_TOK) ? t1 : 0;
        ap0 = Abase + (size_t)t0 * KD + ko;
        ap1 = Abase + (size_t)t1 * KD + ko;
    } else {
        ap0 = Abase + (size_t)(slot0 + ra0) * KD + ko;
        ap1 = Abase + (size_t)(slot0 + ra1) * KD + ko;
    }
    const int ldo0 = (w * 32) * 32;
    const int ldo1 = (w * 32 + 16) * 32;

    // ---- B staging (fp32 native): thread owns col nB, 16 consecutive k
    const int nB = t >> 1;                    // 0..127 (col within tile)
    const int q0 = (t & 1) * 2;               // k-octet pair {0,1} or {2,3}
    const int swzB = ((t >> 3) & 3) << 4;     // = ((nB>>2)&3)<<4
    const float* wsrc = (e < NEXP) ? Wfp + (size_t)e * KD * NC : Wsh;
    const float* wp = wsrc + (size_t)(q0 * 8) * NC + (n0 + nB);

    const int rsw = ((l16 >> 2) & 3) << 4;    // fragment-read swizzle (bytes)

    float rA[16], rB[16];
    floatx4 acc[4][4] = {};

    auto fillA = [&](int slot) {
        gl_lds16(ap0, As + slot * 4096 + ldo0);
        gl_lds16(ap1, As + slot * 4096 + ldo1);
        ap0 += 32; ap1 += 32;
    };
    auto loadB = [&](float (&r)[16]) {
#pragma unroll
        for (int j = 0; j < 16; j++) r[j] = wp[(size_t)j * NC];
        wp += (size_t)32 * NC;
    };
    auto writeB = [&](float (&r)[16], int slot) {
        char* bb = (char*)(Bs + slot * 4096) + nB * 64;
        short8 u0, u1;
#pragma unroll
        for (int i = 0; i < 8; i++) { u0[i] = f2bf(r[i]); u1[i] = f2bf(r[8 + i]); }
        *(short8*)(bb + (((q0 + 0) * 16) ^ swzB)) = u0;
        *(short8*)(bb + (((q0 + 1) * 16) ^ swzB)) = u1;
    };

    // prologue: stages 0,1 issued; B(0) -> LDS; stage 2 issued
    fillA(0); loadB(rA);
    fillA(1); loadB(rB);
    asm volatile("s_waitcnt vmcnt(18)" ::: "memory");   // B(0) regs + A(0) done
    writeB(rA, 0);
    fillA(2); loadB(rA);                                 // stage 2 -> set A

#pragma unroll
    for (int k = 0; k < KI; k++) {
        // retire stage k+1's loads; keep stage k+2 (2 A-dma + 16 B) in flight
        if (k < KI - 2) asm volatile("s_waitcnt vmcnt(18)" ::: "memory");
        else            asm volatile("s_waitcnt vmcnt(0)" ::: "memory");
        if (k + 1 < KI) {                       // stage LDS for next iteration
            if ((k + 1) & 1) writeB(rB, (k + 1) % 3);
            else             writeB(rA, (k + 1) % 3);
        }
        asm volatile("s_waitcnt lgkmcnt(0)" ::: "memory");
        asm volatile("s_barrier" ::: "memory");  // all waves' stage-k data in LDS

        const int s = k % 3;
        short8 af[4], bf[4];
#pragma unroll
        for (int i = 0; i < 4; i++)
            af[i] = *(const short8*)((const char*)(As + s * 4096)
                     + (wr * 64 + i * 16 + l16) * 64 + ((quad * 16) ^ rsw));
#pragma unroll
        for (int j = 0; j < 4; j++)
            bf[j] = *(const short8*)((const char*)(Bs + s * 4096)
                     + (wc * 64 + j * 16 + l16) * 64 + ((quad * 16) ^ rsw));
#pragma unroll
        for (int i = 0; i < 4; i++)
#pragma unroll
            for (int j = 0; j < 4; j++)
                acc[i][j] = __builtin_amdgcn_mfma_f32_16x16x32_bf16(af[i], bf[j], acc[i][j], 0, 0, 0);

        asm volatile("s_waitcnt lgkmcnt(0)" ::: "memory");
        asm volatile("s_barrier" ::: "memory");  // all waves done reading slot s
        if (k + 3 < KI) {                        // refill slot s (= (k+3)%3)
            fillA(s);
            if ((k + 3) & 1) loadB(rB);
            else             loadB(rA);
        }
    }

    // ---- epilogue: restage C tile as bf16 in LDS (XOR col-group swizzle keyed
    // on (row>>2)&3 == quad), then fully-coalesced 16B stores.
    short* const OT = smem;                    // [128][128] bf16 = 32 KiB, LDS free
    const int bias_off = e * NC + n0;
#pragma unroll
    for (int j = 0; j < 4; j++) {
        const int colL = wc * 64 + j * 16 + l16;
        const float bv = bias_all[bias_off + colL];
        const int cg = colL >> 3, wi = colL & 7;
#pragma unroll
        for (int i = 0; i < 4; i++)
#pragma unroll
            for (int r = 0; r < 4; r++) {
                const int rowL = wr * 64 + i * 16 + quad * 4 + r;
                float v = acc[i][j][r] + bv;
                if constexpr (FFN1) v = gelu_erf(v);
                OT[rowL * 128 + (((cg ^ ((rowL >> 2) & 3)) << 3) | wi)] = f2bf(v);
            }
    }
    __syncthreads();
#pragma unroll
    for (int p = 0; p < 8; p++) {
        const int rowL = p * 16 + (t >> 4);
        const int g = t & 15;
        const short8 v = *(const short8*)(OT + rowL * 128 + ((g ^ ((rowL >> 2) & 3)) << 3));
        *(short8*)&outb[(size_t)(slot0 + rowL) * NC + n0 + g * 8] = v;
    }
}

// ------------------------------------------- combine: out[n] = y_shared + sum w_k y_k
__global__ __launch_bounds__(256) void combine_kernel(
    const short* __restrict__ ybuf, const int* __restrict__ slot_of_tok,
    const float* __restrict__ top_w, float* __restrict__ out)
{
    const int n = blockIdx.x;
    const int c = threadIdx.x;
    const int s0 = slot_of_tok[n * 4 + 0];
    const int s1 = slot_of_tok[n * 4 + 1];
    const int s2 = slot_of_tok[n * 4 + 2];
    const int ss = slot_of_tok[n * 4 + 3];
    const float w0 = top_w[n * 3 + 0];
    const float w1 = top_w[n * 3 + 1];
    const float w2 = top_w[n * 3 + 2];

    short4 y0 = ((const short4*)(ybuf + (size_t)s0 * DDIM))[c];
    short4 y1 = ((const short4*)(ybuf + (size_t)s1 * DDIM))[c];
    short4 y2 = ((const short4*)(ybuf + (size_t)s2 * DDIM))[c];
    short4 ys = ((const short4*)(ybuf + (size_t)ss * DDIM))[c];

    float4 o;
    o.x = bf2f(ys.x) + w0 * bf2f(y0.x) + w1 * bf2f(y1.x) + w2 * bf2f(y2.x);
    o.y = bf2f(ys.y) + w0 * bf2f(y0.y) + w1 * bf2f(y1.y) + w2 * bf2f(y2.y);
    o.z = bf2f(ys.z) + w0 * bf2f(y0.z) + w1 * bf2f(y1.z) + w2 * bf2f(y2.z);
    o.w = bf2f(ys.w) + w0 * bf2f(y0.w) + w1 * bf2f(y1.w) + w2 * bf2f(y2.w);
    ((float4*)(out + (size_t)n * DDIM))[c] = o;
}

// ---------------------------------------------------------------------- launch
extern "C" void kernel_launch(void* const* d_in, const int* in_sizes, int n_in,
                              void* d_out, int out_size, void* d_ws, size_t ws_size,
                              hipStream_t stream)
{
    const float* x          = (const float*)d_in[0];
    const float* gate_W     = (const float*)d_in[1];
    const float* gate_b     = (const float*)d_in[2];
    const float* route_bias = (const float*)d_in[3];
    const float* W1         = (const float*)d_in[4];
    const float* b1         = (const float*)d_in[5];
    const float* W2         = (const float*)d_in[6];
    const float* b2         = (const float*)d_in[7];
    const float* sW1        = (const float*)d_in[8];
    const float* sb1        = (const float*)d_in[9];
    const float* sW2        = (const float*)d_in[10];
    const float* sb2        = (const float*)d_in[11];
    float* out = (float*)d_out;

    uint8_t* ws = (uint8_t*)d_ws;
    int*   top_idx   = (int*)(ws);                    //      49152
    float* top_w     = (float*)(ws + 49152);          //      49152
    int*   tile_e    = (int*)(ws + 98688);            //        640
    float* psum_part = (float*)(ws + 99328);          //      94208
    int*   tok_slot  = (int*)(ws + 193536);           //      77824 (SLOTS)
    int*   slot_tok  = (int*)(ws + 271360);           //      65536 [N][4]
    float* bias1_all = (float*)(ws + 336896);         //      73728 [24][H]
    float* bias2_all = (float*)(ws + 410624);         //      98304 [24][D]
    short* xb        = (short*)(ws + 512000);         //    8388608 [N][D]
    short* hbuf      = (short*)(ws + 8900608);        //   29884416 [SLOTS][H]
    short* ybuf      = (short*)(ws + 38785024);       //   39845888 [SLOTS][D]

    prep_kernel<<<PREP_GRID, 256, 0, stream>>>(
        x, gate_W, gate_b, route_bias, top_idx, top_w, psum_part,
        xb, b1, sb1, b2, sb2, bias1_all, bias2_all);
    plan_kernel<<<1, 256, 0, stream>>>(top_idx, psum_part, tile_e,
                                       tok_slot, slot_tok,
                                       out + (size_t)N_TOK * DDIM);

    gemm_kernel<true><<<dim3(HDIM / 128, MAXTILE), 256, 0, stream>>>(
        xb, tok_slot, tile_e, W1, sW1, bias1_all, hbuf);
    gemm_kernel<false><<<dim3(DDIM / 128, MAXTILE), 256, 0, stream>>>(
        hbuf, tok_slot, tile_e, W2, sW2, bias2_all, ybuf);
    combine_kernel<<<N_TOK, 256, 0, stream>>>(ybuf, slot_tok, top_w, out);
}

// Round 4
// 410.885 us; speedup vs baseline: 1.2524x; 1.2524x over previous
//
#include <hip/hip_runtime.h>
#include <hip/hip_bf16.h>
#include <stdint.h>

#define N_TOK 4096
#define DDIM  1024
#define HDIM  768
#define NEXP  23
#define TOPK  3
#define MAXTILE 152            // <=119 routed tiles + 32 shared tiles
#define SLOTS   19456

typedef float floatx4 __attribute__((ext_vector_type(4)));
typedef short short8  __attribute__((ext_vector_type(8)));

__device__ __forceinline__ short f2bf(float f) {
    __hip_bfloat16 h = __float2bfloat16(f);
    return *reinterpret_cast<short*>(&h);
}
__device__ __forceinline__ float bf2f(short s) {
    unsigned u = ((unsigned)(unsigned short)s) << 16;
    return __uint_as_float(u);
}
__device__ __forceinline__ float gelu_erf(float v) {
    return 0.5f * v * (1.0f + erff(v * 0.70710678118654752f));
}
// async global->LDS, 16B/lane; LDS dest wave-uniform base (HW adds lane*16)
__device__ __forceinline__ void gl_lds16(const short* g, short* l) {
    __builtin_amdgcn_global_load_lds(
        (const __attribute__((address_space(1))) void*)g,
        (__attribute__((address_space(3))) void*)l, 16, 0, 0);
}

// block-role bases for the fused prep kernel
#define PREP_GATE   1024
#define PREP_XCVT   N_TOK                 // 4096 blocks
#define PREP_BIAS   168                   // 24*(H+D)/256
#define PREP_TCVT   2304                  // 2 * 24 * 48 (128x128 tiles)
#define PREP_GRID   (PREP_GATE + PREP_XCVT + PREP_BIAS + PREP_TCVT)

// ------- fused: gate+topk | x fp32->bf16 | bias concat | weight cvt+transpose
__global__ __launch_bounds__(256) void prep_kernel(
    const float* __restrict__ x, const float* __restrict__ gate_W,
    const float* __restrict__ gate_b, const float* __restrict__ route_bias,
    int* __restrict__ top_idx, float* __restrict__ top_w,
    float* __restrict__ psum_part, short* __restrict__ xb,
    const float* __restrict__ b1, const float* __restrict__ sb1,
    const float* __restrict__ b2, const float* __restrict__ sb2,
    float* __restrict__ bias1_all, float* __restrict__ bias2_all,
    const float* __restrict__ W1, const float* __restrict__ sW1, short* __restrict__ W1T,
    const float* __restrict__ W2, const float* __restrict__ sW2, short* __restrict__ W2T)
{
    __shared__ float ps[4][NEXP];
    const int b = blockIdx.x;
    if (b >= PREP_GATE) {
        const int bb = b - PREP_GATE;
        if (bb < PREP_XCVT) {             // x convert: one float4/thread
            size_t i = (size_t)bb * 256 + threadIdx.x;
            float4 v = ((const float4*)x)[i];
            short4 o;
            o.x = f2bf(v.x); o.y = f2bf(v.y); o.z = f2bf(v.z); o.w = f2bf(v.w);
            ((short4*)xb)[i] = o;
        } else if (bb < PREP_XCVT + PREP_BIAS) {   // bias concat
            int i = (bb - PREP_XCVT) * 256 + threadIdx.x;
            if (i < 24 * HDIM) {
                bias1_all[i] = (i < NEXP * HDIM) ? b1[i] : sb1[i - NEXP * HDIM];
            } else {
                int j = i - 24 * HDIM;
                if (j < 24 * DDIM)
                    bias2_all[j] = (j < NEXP * DDIM) ? b2[j] : sb2[j - NEXP * DDIM];
            }
        } else {
            // weight transpose+convert: 128x128 tile, 8x8 micro-tile per
            // thread, pure register transpose (no LDS, no bank conflicts).
            // Stores are lane-consecutive == row-consecutive: 256B segments.
            int idx = bb - (PREP_XCVT + PREP_BIAS);
            const float* s; short* d; int R, C, rt, ct;
            if (idx < 24 * 48) {
                const int wz = idx / 48, rem = idx % 48;
                R = DDIM; C = HDIM;                 // src [1024][768]
                rt = (rem / 6) * 128; ct = (rem % 6) * 128;
                s = (wz < NEXP) ? W1 + (size_t)wz * DDIM * HDIM : sW1;
                d = W1T + (size_t)wz * DDIM * HDIM;
            } else {
                idx -= 24 * 48;
                const int wz = idx / 48, rem = idx % 48;
                R = HDIM; C = DDIM;                 // src [768][1024]
                rt = (rem / 8) * 128; ct = (rem % 8) * 128;
                s = (wz < NEXP) ? W2 + (size_t)wz * HDIM * DDIM : sW2;
                d = W2T + (size_t)wz * HDIM * DDIM;
            }
            const int t = threadIdx.x;
            const int u = t & 15, q = t >> 4;       // u fast -> coalesced stores
            const int r0 = rt + 8 * u, c0 = ct + 8 * q;
            float4 f[8][2];
#pragma unroll
            for (int i = 0; i < 8; i++) {
                f[i][0] = *(const float4*)&s[(size_t)(r0 + i) * C + c0];
                f[i][1] = *(const float4*)&s[(size_t)(r0 + i) * C + c0 + 4];
            }
#pragma unroll
            for (int j = 0; j < 8; j++) {
                const int hh = j >> 2, jj = j & 3;
                short8 col;
#pragma unroll
                for (int i = 0; i < 8; i++) {
                    float v = (jj == 0) ? f[i][hh].x :
                              (jj == 1) ? f[i][hh].y :
                              (jj == 2) ? f[i][hh].z : f[i][hh].w;
                    col[i] = f2bf(v);
                }
                *(short8*)&d[(size_t)(c0 + j) * R + r0] = col;
            }
        }
        return;
    }
    // ---- gate: one wave per token, fp32-exact, BARRIER-FREE.
    // Lane l owns d = {l, l+64, ...}; reads gate_W rows directly (94 KB total,
    // L1/L2-resident after first touch). Per-lane accumulation order and the
    // shuffle reduce are bit-identical to the previous LDS-staged version.
    const int wave = threadIdx.x >> 6, lane = threadIdx.x & 63;
    const int n = b * 4 + wave;

    float acc[NEXP];
#pragma unroll
    for (int e = 0; e < NEXP; e++) acc[e] = 0.f;

    const float* xr = x + (size_t)n * DDIM;
#pragma unroll 4
    for (int c = 0; c < DDIM / 64; c++) {
        const int d = c * 64 + lane;
        const float xd = xr[d];
        const float* wrow = gate_W + (size_t)d * NEXP;
#pragma unroll
        for (int e = 0; e < NEXP; e++) acc[e] = fmaf(xd, wrow[e], acc[e]);
    }
    for (int off = 32; off > 0; off >>= 1) {
#pragma unroll
        for (int e = 0; e < NEXP; e++) acc[e] += __shfl_xor(acc[e], off, 64);
    }

    float p[NEXP], s = 0.f;
#pragma unroll
    for (int e = 0; e < NEXP; e++) {
        p[e] = 1.f / (1.f + expf(-(acc[e] + gate_b[e])));
        s += p[e];
    }
    const float inv = 1.f / s;

    if (lane == 0) {
#pragma unroll
        for (int e = 0; e < NEXP; e++) ps[wave][e] = p[e] * inv;
        // top-3, strict > picks lowest index on ties (lax.top_k rule)
        int idx[TOPK]; float w[TOPK]; bool used[NEXP] = {};
        for (int k = 0; k < TOPK; k++) {
            float best = -1e30f; int bi = 0;
            for (int e = 0; e < NEXP; e++) {
                if (!used[e]) {
                    float sc = p[e] + route_bias[e];
                    if (sc > best) { best = sc; bi = e; }
                }
            }
            used[bi] = true; idx[k] = bi; w[k] = p[bi];
        }
        float wsum = w[0] + w[1] + w[2];
        for (int k = 0; k < TOPK; k++) {
            top_idx[n * TOPK + k] = idx[k];
            top_w[n * TOPK + k]   = w[k] / wsum;
        }
    }
    __syncthreads();
    if (threadIdx.x < NEXP) {
        int e = threadIdx.x;
        psum_part[(size_t)b * NEXP + e] =
            ps[0][e] + ps[1][e] + ps[2][e] + ps[3][e];
    }
}

// ---------- plan+scatter: counts, aux loss, tile table, slot maps (1 block)
__global__ __launch_bounds__(256) void plan_kernel(
    const int* __restrict__ top_idx, const float* __restrict__ psum_part,
    int* __restrict__ tile_e, int* __restrict__ tok_of_slot,
    int* __restrict__ slot_of_tok, float* __restrict__ out_aux)
{
    __shared__ int   cnt[NEXP];
    __shared__ float psum[NEXP];
    __shared__ int   tbase[NEXP + 1];
    __shared__ int   lcur[NEXP];
    const int t = threadIdx.x;
    if (t < NEXP) { cnt[t] = 0; psum[t] = 0.f; lcur[t] = 0; }
    __syncthreads();

    for (int i = t; i < N_TOK * TOPK; i += 256)
        atomicAdd(&cnt[top_idx[i]], 1);

    float loc[NEXP];
#pragma unroll
    for (int e = 0; e < NEXP; e++) loc[e] = 0.f;
    for (int b = t; b < N_TOK / 4; b += 256) {
        const float* row = psum_part + (size_t)b * NEXP;
#pragma unroll
        for (int e = 0; e < NEXP; e++) loc[e] += row[e];
    }
#pragma unroll
    for (int e = 0; e < NEXP; e++) atomicAdd(&psum[e], loc[e]);
    __syncthreads();

    if (t == 0) {
        int tb = 0; float aux = 0.f;
        for (int e = 0; e < NEXP; e++) {
            tbase[e] = tb;
            float P = psum[e] / (float)N_TOK;
            float F = (float)NEXP * (float)cnt[e] / ((float)TOPK * (float)N_TOK);
            aux += P * F;
            tb += (cnt[e] + 127) >> 7;
        }
        tbase[NEXP] = tb;
        *out_aux = aux;
    }
    __syncthreads();
    const int tr = tbase[NEXP];
    const int P  = tr << 7;
    for (int i = t; i < MAXTILE; i += 256) {
        int v = -1;
        if (i < tr) {
            for (int e = 0; e < NEXP; e++)
                if (i >= tbase[e] && i < tbase[e + 1]) v = e;
        } else if (i < tr + N_TOK / 128) v = NEXP;
        tile_e[i] = v;
    }
    // scatter (LDS-atomic cursors; pad slots left undefined, gemm clamps)
    for (int i = t; i < N_TOK * TOPK; i += 256) {
        const int e = top_idx[i];
        const int pos = atomicAdd(&lcur[e], 1);
        const int slot = (tbase[e] << 7) + pos;
        const int n = i / 3, k = i - n * 3;
        tok_of_slot[slot] = n;
        slot_of_tok[n * 4 + k] = slot;
    }
    for (int n = t; n < N_TOK; n += 256) {
        tok_of_slot[P + n] = n;            // shared expert: identity mapping
        slot_of_tok[n * 4 + 3] = P + n;
    }
}

// --------------------------------------------------------------- unified GEMM
// 128x128 tile, BK=32, 3-stage async pipeline: raw s_barrier + fine vmcnt so
// prefetched global_load_lds stay in flight across barriers (no vmcnt(0) drain).
// + bijective XCD swizzle (expert weight panels stay in one XCD's L2)
// + LDS-restaged epilogue (16B coalesced stores, kills 2x write amplification)
template <bool FFN1>
__global__ __launch_bounds__(256) void gemm_kernel(
    const short* __restrict__ Abase, const int* __restrict__ tok_of_slot,
    const int* __restrict__ tile_e, const short* __restrict__ Wall,
    const float* __restrict__ bias_all, short* __restrict__ outb)
{
    constexpr int KD = FFN1 ? DDIM : HDIM;
    constexpr int NC = FFN1 ? HDIM : DDIM;
    constexpr int KI = KD / 32;
    constexpr int GX = NC / 128;
    constexpr int NWG = GX * MAXTILE;
    constexpr int Q = NWG / 8, RM = NWG % 8;

    int bid = blockIdx.y * GX + blockIdx.x;
    {   // bijective chunked XCD swizzle: bid%8 -> contiguous chunk of tile space
        const int xcd = bid & 7, off = bid >> 3;
        bid = (xcd < RM) ? (xcd * (Q + 1) + off)
                         : (RM * (Q + 1) + (xcd - RM) * Q + off);
    }
    const int tile = bid / GX;
    const int e = tile_e[tile];
    if (e < 0) return;
    const int slot0 = tile * 128;
    const int n0 = (bid - tile * GX) * 128;

    __shared__ short smem[3 * 4096 * 2];       // 48 KiB: As[3] | Bs[3]
    short* const As = smem;
    short* const Bs = smem + 3 * 4096;

    const int t = threadIdx.x;
    const int w = t >> 6, l = t & 63;
    const int quad = l >> 4, l16 = l & 15;
    const int wr = w >> 1, wc = w & 1;

    const int ra0 = w * 32 + (l >> 2);
    const int ra1 = ra0 + 16;
    const int ko  = (l & 3) << 3;

    const short *ap0, *ap1;
    if constexpr (FFN1) {
        int t0 = tok_of_slot[slot0 + ra0];
        int t1 = tok_of_slot[slot0 + ra1];
        t0 = ((unsigned)t0 < (unsigned)N_TOK) ? t0 : 0;  // pad slots: any valid row
        t1 = ((unsigned)t1 < (unsigned)N_TOK) ? t1 : 0;
        ap0 = Abase + (size_t)t0 * KD + ko;
        ap1 = Abase + (size_t)t1 * KD + ko;
    } else {
        ap0 = Abase + (size_t)(slot0 + ra0) * KD + ko;
        ap1 = Abase + (size_t)(slot0 + ra1) * KD + ko;
    }
    const short* bbase = Wall + (size_t)e * NC * KD + (size_t)n0 * KD;
    const short* bp0 = bbase + (size_t)ra0 * KD + ko;
    const short* bp1 = bbase + (size_t)ra1 * KD + ko;

    const int ldo0 = (w * 32) * 32;
    const int ldo1 = (w * 32 + 16) * 32;

    floatx4 acc[4][4] = {};

    // prologue: 3 k-groups in flight (12 vmem instrs/wave)
#pragma unroll
    for (int p = 0; p < 3; p++) {
        gl_lds16(ap0, As + p * 4096 + ldo0); gl_lds16(ap1, As + p * 4096 + ldo1);
        gl_lds16(bp0, Bs + p * 4096 + ldo0); gl_lds16(bp1, Bs + p * 4096 + ldo1);
        ap0 += 32; ap1 += 32; bp0 += 32; bp1 += 32;
    }

#pragma unroll
    for (int k = 0; k < KI; k++) {
        // retire exactly the oldest group (4 instrs); keep the rest in flight
        if (k < KI - 2)       asm volatile("s_waitcnt vmcnt(8)" ::: "memory");
        else if (k == KI - 2) asm volatile("s_waitcnt vmcnt(4)" ::: "memory");
        else                  asm volatile("s_waitcnt vmcnt(0)" ::: "memory");
        asm volatile("s_barrier" ::: "memory");   // all waves' group-k data in LDS

        const int s = k % 3;
        short8 af[4], bf[4];
#pragma unroll
        for (int i = 0; i < 4; i++)
            af[i] = *(const short8*)(As + s * 4096 + (wr * 64 + i * 16 + l16) * 32 + quad * 8);
#pragma unroll
        for (int j = 0; j < 4; j++)
            bf[j] = *(const short8*)(Bs + s * 4096 + (wc * 64 + j * 16 + l16) * 32 + quad * 8);
#pragma unroll
        for (int i = 0; i < 4; i++)
#pragma unroll
            for (int j = 0; j < 4; j++)
                acc[i][j] = __builtin_amdgcn_mfma_f32_16x16x32_bf16(af[i], bf[j], acc[i][j], 0, 0, 0);

        asm volatile("s_waitcnt lgkmcnt(0)" ::: "memory");
        asm volatile("s_barrier" ::: "memory");   // all waves done reading slot s
        if (k + 3 < KI) {                          // refill slot s (= (k+3)%3)
            gl_lds16(ap0, As + s * 4096 + ldo0); gl_lds16(ap1, As + s * 4096 + ldo1);
            gl_lds16(bp0, Bs + s * 4096 + ldo0); gl_lds16(bp1, Bs + s * 4096 + ldo1);
            ap0 += 32; ap1 += 32; bp0 += 32; bp1 += 32;
        }
    }

    // ---- epilogue: restage C tile as bf16 in LDS (XOR col-group swizzle keyed
    // on (row>>2)&3 == quad), then fully-coalesced 16B stores.
    short* const OT = smem;                    // [128][128] bf16 = 32 KiB, LDS free
    const int bias_off = e * NC + n0;
#pragma unroll
    for (int j = 0; j < 4; j++) {
        const int colL = wc * 64 + j * 16 + l16;
        const float bv = bias_all[bias_off + colL];
        const int cg = colL >> 3, wi = colL & 7;
#pragma unroll
        for (int i = 0; i < 4; i++)
#pragma unroll
            for (int r = 0; r < 4; r++) {
                const int rowL = wr * 64 + i * 16 + quad * 4 + r;
                float v = acc[i][j][r] + bv;
                if constexpr (FFN1) v = gelu_erf(v);
                OT[rowL * 128 + (((cg ^ ((rowL >> 2) & 3)) << 3) | wi)] = f2bf(v);
            }
    }
    __syncthreads();
#pragma unroll
    for (int p = 0; p < 8; p++) {
        const int rowL = p * 16 + (t >> 4);
        const int g = t & 15;
        const short8 v = *(const short8*)(OT + rowL * 128 + ((g ^ ((rowL >> 2) & 3)) << 3));
        *(short8*)&outb[(size_t)(slot0 + rowL) * NC + n0 + g * 8] = v;
    }
}

// ------------------------------------------- combine: out[n] = y_shared + sum w_k y_k
__global__ __launch_bounds__(256) void combine_kernel(
    const short* __restrict__ ybuf, const int* __restrict__ slot_of_tok,
    const float* __restrict__ top_w, float* __restrict__ out)
{
    const int n = blockIdx.x;
    const int c = threadIdx.x;
    const int s0 = slot_of_tok[n * 4 + 0];
    const int s1 = slot_of_tok[n * 4 + 1];
    const int s2 = slot_of_tok[n * 4 + 2];
    const int ss = slot_of_tok[n * 4 + 3];
    const float w0 = top_w[n * 3 + 0];
    const float w1 = top_w[n * 3 + 1];
    const float w2 = top_w[n * 3 + 2];

    short4 y0 = ((const short4*)(ybuf + (size_t)s0 * DDIM))[c];
    short4 y1 = ((const short4*)(ybuf + (size_t)s1 * DDIM))[c];
    short4 y2 = ((const short4*)(ybuf + (size_t)s2 * DDIM))[c];
    short4 ys = ((const short4*)(ybuf + (size_t)ss * DDIM))[c];

    float4 o;
    o.x = bf2f(ys.x) + w0 * bf2f(y0.x) + w1 * bf2f(y1.x) + w2 * bf2f(y2.x);
    o.y = bf2f(ys.y) + w0 * bf2f(y0.y) + w1 * bf2f(y1.y) + w2 * bf2f(y2.y);
    o.z = bf2f(ys.z) + w0 * bf2f(y0.z) + w1 * bf2f(y1.z) + w2 * bf2f(y2.z);
    o.w = bf2f(ys.w) + w0 * bf2f(y0.w) + w1 * bf2f(y1.w) + w2 * bf2f(y2.w);
    ((float4*)(out + (size_t)n * DDIM))[c] = o;
}

// ---------------------------------------------------------------------- launch
extern "C" void kernel_launch(void* const* d_in, const int* in_sizes, int n_in,
                              void* d_out, int out_size, void* d_ws, size_t ws_size,
                              hipStream_t stream)
{
    const float* x          = (const float*)d_in[0];
    const float* gate_W     = (const float*)d_in[1];
    const float* gate_b     = (const float*)d_in[2];
    const float* route_bias = (const float*)d_in[3];
    const float* W1         = (const float*)d_in[4];
    const float* b1         = (const float*)d_in[5];
    const float* W2         = (const float*)d_in[6];
    const float* b2         = (const float*)d_in[7];
    const float* sW1        = (const float*)d_in[8];
    const float* sb1        = (const float*)d_in[9];
    const float* sW2        = (const float*)d_in[10];
    const float* sb2        = (const float*)d_in[11];
    float* out = (float*)d_out;

    uint8_t* ws = (uint8_t*)d_ws;
    int*   top_idx   = (int*)(ws);                    //      49152
    float* top_w     = (float*)(ws + 49152);          //      49152
    int*   tile_e    = (int*)(ws + 98688);            //        640
    float* psum_part = (float*)(ws + 99328);          //      94208
    int*   tok_slot  = (int*)(ws + 193536);           //      77824 (SLOTS)
    int*   slot_tok  = (int*)(ws + 271360);           //      65536 [N][4]
    float* bias1_all = (float*)(ws + 336896);         //      73728 [24][H]
    float* bias2_all = (float*)(ws + 410624);         //      98304 [24][D]
    short* xb        = (short*)(ws + 512000);         //    8388608 [N][D]
    short* W1T       = (short*)(ws + 8902656);        //   37748736 [24][H][D]
    short* W2T       = (short*)(ws + 46651392);       //   37748736 [24][D][H]
    short* hbuf      = (short*)(ws + 84400128);       //   29884416 [SLOTS][H]
    short* ybuf      = (short*)(ws + 512000);         //   39845888 [SLOTS][D] — aliases
                      // xb+W1T (both dead after gemm1; gemm2/combine don't touch them)

    prep_kernel<<<PREP_GRID, 256, 0, stream>>>(
        x, gate_W, gate_b, route_bias, top_idx, top_w, psum_part,
        xb, b1, sb1, b2, sb2, bias1_all, bias2_all,
        W1, sW1, W1T, W2, sW2, W2T);
    plan_kernel<<<1, 256, 0, stream>>>(top_idx, psum_part, tile_e,
                                       tok_slot, slot_tok,
                                       out + (size_t)N_TOK * DDIM);

    gemm_kernel<true><<<dim3(HDIM / 128, MAXTILE), 256, 0, stream>>>(
        xb, tok_slot, tile_e, W1T, bias1_all, hbuf);
    gemm_kernel<false><<<dim3(DDIM / 128, MAXTILE), 256, 0, stream>>>(
        hbuf, tok_slot, tile_e, W2T, bias2_all, ybuf);
    combine_kernel<<<N_TOK, 256, 0, stream>>>(ybuf, slot_tok, top_w, out);
}